// Round 5
// baseline (1711.019 us; speedup 1.0000x reference)
//
#include <hip/hip_runtime.h>

#define BB 256
#define TT 1024
#define II 128
#define GG 512   // 2C
#define CC 256
#define L2E 1.44269504f

typedef _Float16 f16;
typedef _Float16 h8_t __attribute__((ext_vector_type(8)));
typedef float f4_t __attribute__((ext_vector_type(4)));
typedef unsigned short ushort_t;

static __device__ __forceinline__ float fast_rcp(float x) {
#if __has_builtin(__builtin_amdgcn_rcpf)
    return __builtin_amdgcn_rcpf(x);
#else
    return 1.f / x;
#endif
}
static __device__ __forceinline__ float fast_exp2(float x) {
#if __has_builtin(__builtin_amdgcn_exp2f)
    return __builtin_amdgcn_exp2f(x);
#else
    return exp2f(x);
#endif
}

// ---- kernel 1: Kt[n][k] = f16(kernel[k][n])  (128x512 -> 512x128) ----
__global__ void kt_transpose(const float* __restrict__ kin, f16* __restrict__ kt) {
    int idx = blockIdx.x * 256 + threadIdx.x;   // 65536 total
    int k = idx >> 9;
    int n = idx & 511;
    kt[n * II + k] = (f16)kin[k * GG + n];
}

// ---- kernel 2: xzT[t][b][512] = f16( (x@K + bias) * s_col ), s = L2E (f) / 2*L2E (g) ----
// m' = t*256 + b. Epilogue restages through LDS so global stores are 16 B/lane.
__global__ __launch_bounds__(256)
void gemm_xz(const float* __restrict__ x, const f16* __restrict__ kt,
             const float* __restrict__ bias, ushort_t* __restrict__ xz) {
    const int  ntile = blockIdx.x;   // 0..3   (128 cols)
    const long mtile = blockIdx.y;   // 0..2047 (128 rows of m')
    const int wave = threadIdx.x >> 6;
    const int lane = threadIdx.x & 63;
    const int wm = (wave & 1) * 64;
    const int wn = (wave >> 1) * 64;
    const int lm = lane & 15;
    const int q  = lane >> 4;

    f4_t acc[4][4];
#pragma unroll
    for (int mi = 0; mi < 4; ++mi)
#pragma unroll
        for (int ni = 0; ni < 4; ++ni)
            acc[mi][ni] = (f4_t){0.f, 0.f, 0.f, 0.f};

#pragma unroll
    for (int kc = 0; kc < 4; ++kc) {
        h8_t a[4], bf[4];
#pragma unroll
        for (int mi = 0; mi < 4; ++mi) {
            const int rowm = (int)(mtile * 128) + wm + mi * 16 + lm;   // m'
            const int b  = rowm & 255;
            const int tt = rowm >> 8;
            const float* ap = x + (size_t)b * (TT * II) + (size_t)tt * II + kc * 32 + q * 8;
            f4_t p0 = *(const f4_t*)ap;
            f4_t p1 = *(const f4_t*)(ap + 4);
            h8_t tv;
            tv[0] = (f16)p0[0]; tv[1] = (f16)p0[1]; tv[2] = (f16)p0[2]; tv[3] = (f16)p0[3];
            tv[4] = (f16)p1[0]; tv[5] = (f16)p1[1]; tv[6] = (f16)p1[2]; tv[7] = (f16)p1[3];
            a[mi] = tv;
        }
#pragma unroll
        for (int ni = 0; ni < 4; ++ni) {
            const f16* bp = kt + (size_t)(ntile * 128 + wn + ni * 16 + lm) * II + kc * 32 + q * 8;
            bf[ni] = *(const h8_t*)bp;
        }
#pragma unroll
        for (int mi = 0; mi < 4; ++mi)
#pragma unroll
            for (int ni = 0; ni < 4; ++ni)
                acc[mi][ni] = __builtin_amdgcn_mfma_f32_16x16x32_f16(a[mi], bf[ni], acc[mi][ni], 0, 0, 0);
    }

    // epilogue: frags -> LDS f16 tile -> coalesced dwordx4 stores
    __shared__ __align__(16) f16 st[128][136];   // 136 = 128 + 8 pad (16B-aligned rows)
#pragma unroll
    for (int mi = 0; mi < 4; ++mi) {
#pragma unroll
        for (int ni = 0; ni < 4; ++ni) {
            const int col = ntile * 128 + wn + ni * 16 + lm;
            const float bv = bias[col];
            const float s  = (col < CC) ? L2E : (2.0f * L2E);
#pragma unroll
            for (int r = 0; r < 4; ++r)
                st[wm + mi * 16 + q * 4 + r][wn + ni * 16 + lm] = (f16)((acc[mi][ni][r] + bv) * s);
        }
    }
    __syncthreads();
    {
        const int r0  = threadIdx.x >> 1;         // local row 0..127
        const int seg = threadIdx.x & 1;          // 64-col half
        ushort_t* gp = xz + (size_t)(mtile * 128 + r0) * GG + ntile * 128 + seg * 64;
        const f16* lp = &st[r0][seg * 64];
#pragma unroll
        for (int j = 0; j < 8; ++j)
            *(f4_t*)(gp + j * 8) = *(const f4_t*)(lp + j * 8);
    }
}

// ---- kernel 3: MFMA recurrence. 16 WGs x 512 thr, 16 batches per WG. ----
// Wave w owns n-tiles {w, w+8, w+16, w+24} = 2 (f,g) pairs: (w, w+16) and (w+8, w+24).
// Pair-0 MFMA chains run first (af reads interleaved); pair-0 gates are emitted
// between pair-1's independent MFMAs so VALU/trans overlap matrix-pipe time.
// acc starts at 0; xz added at gate time. Raw lgkmcnt-only barrier keeps the
// global xz prefetch (issued at end of step, consumed 2 steps later) in flight.
#define GATES(P, AF_, AG_, PF, HWR) do {                                             \
    _Pragma("unroll") for (int r = 0; r < 4; ++r) {                                  \
        ushort_t uf = (PF)[(P) * 4 + r];                                             \
        ushort_t ug = (PF)[((P) + 2) * 4 + r];                                       \
        float zf = (AF_)[r] + (float)(*(f16*)&uf);                                   \
        float zg = (AG_)[r] + (float)(*(f16*)&ug);                                   \
        float ef = fast_exp2(-zf);                                                   \
        float eg = fast_exp2(-fabsf(zg));                                            \
        unsigned sg = __builtin_bit_cast(unsigned, zg) & 0x80000000u;                \
        float t1 = __builtin_bit_cast(float, __builtin_bit_cast(unsigned, ef) ^ sg); \
        float cv = cst[P][r];                                                        \
        float num = fmaf(cv, eg, cv) + fmaf(-t1, eg, t1);                            \
        float den = (1.f + ef) * (1.f + eg);                                         \
        cv = num * fast_rcp(den);                                                    \
        cst[P][r] = cv;                                                              \
        (HWR)[(q * 4 + r) * 264 + (wave + 8 * (P)) * 16 + lm] = (f16)cv;             \
    }                                                                                \
} while (0)

#define STEP(T, PF, PP, HRD, HWR) do {                                               \
    h8_t af[8];                                                                      \
    af[0] = *(const h8_t*)((HRD) + lm * 264 + 0 * 32 + q * 8);                       \
    af[1] = *(const h8_t*)((HRD) + lm * 264 + 1 * 32 + q * 8);                       \
    f4_t a0 = (f4_t){0.f,0.f,0.f,0.f}, a1 = (f4_t){0.f,0.f,0.f,0.f};                 \
    f4_t a2 = (f4_t){0.f,0.f,0.f,0.f}, a3 = (f4_t){0.f,0.f,0.f,0.f};                 \
    _Pragma("unroll") for (int kt = 0; kt < 8; ++kt) {                               \
        if (kt < 6) af[kt + 2] = *(const h8_t*)((HRD) + lm * 264 + (kt + 2) * 32 + q * 8); \
        a0 = __builtin_amdgcn_mfma_f32_16x16x32_f16(af[kt], bw[0][kt], a0, 0, 0, 0); \
        a2 = __builtin_amdgcn_mfma_f32_16x16x32_f16(af[kt], bw[2][kt], a2, 0, 0, 0); \
    }                                                                                \
    _Pragma("unroll") for (int kt = 0; kt < 8; ++kt) {                               \
        a1 = __builtin_amdgcn_mfma_f32_16x16x32_f16(af[kt], bw[1][kt], a1, 0, 0, 0); \
        a3 = __builtin_amdgcn_mfma_f32_16x16x32_f16(af[kt], bw[3][kt], a3, 0, 0, 0); \
    }                                                                                \
    GATES(0, a0, a2, PF, HWR);                                                       \
    GATES(1, a1, a3, PF, HWR);                                                       \
    if ((T) + 2 < TT) {                                                              \
        _Pragma("unroll") for (int ni = 0; ni < 4; ++ni)                             \
            _Pragma("unroll") for (int r = 0; r < 4; ++r)                            \
                (PF)[ni * 4 + r] = (PP)[r * 512 + ni * 128];                         \
        (PP) += 2 * 131072;                                                          \
    }                                                                                \
    asm volatile("s_waitcnt lgkmcnt(0)\n\ts_barrier" ::: "memory");                  \
} while (0)

__global__ __launch_bounds__(512, 2)
void janet_rec(const float* __restrict__ rk, const float* __restrict__ dw,
               const float* __restrict__ db, const ushort_t* __restrict__ xz,
               float* __restrict__ out) {
    const int g = blockIdx.x;            // batch group: batches g*16 .. g*16+15
    const int tid = threadIdx.x;
    const int wave = tid >> 6;
    const int lane = tid & 63;
    const int lm = lane & 15;
    const int q  = lane >> 4;

    // resident pre-scaled recurrent weights: bw[ni][kt][j] = s * R[kt*32+q*8+j][(wave+8*ni)*16+lm]
    h8_t bw[4][8];
#pragma unroll
    for (int ni = 0; ni < 4; ++ni) {
        const float s = (ni < 2) ? L2E : (2.0f * L2E);
#pragma unroll
        for (int kt = 0; kt < 8; ++kt) {
            h8_t tv;
#pragma unroll
            for (int j = 0; j < 8; ++j)
                tv[j] = (f16)(s * rk[(size_t)(kt * 32 + q * 8 + j) * GG + (wave + 8 * ni) * 16 + lm]);
            bw[ni][kt] = tv;
        }
    }

    __shared__ __align__(16) f16 hb[2][16][264];
    f16* h0 = &hb[0][0][0];
    f16* h1 = &hb[1][0][0];
    for (int i = tid; i < 2 * 16 * 264; i += 512) ((f16*)hb)[i] = (f16)0.f;

    float cst[2][4];
#pragma unroll
    for (int ni = 0; ni < 2; ++ni)
#pragma unroll
        for (int r = 0; r < 4; ++r) cst[ni][r] = 0.f;

    // per-thread xzT base (t-major): value(t, row=q*4+r, col=(wave+8*ni)*16+lm) at
    //   base(t)[r*512 + ni*128],  base(t) = xz + (t*256 + g*16 + q*4)*512 + wave*16 + lm
    const ushort_t* pb = xz + ((size_t)g * 16 + q * 4) * 512 + wave * 16 + lm;
    const ushort_t* p1b = pb + 131072;          // t=1
    const ushort_t* p0 = pb + 2 * 131072;       // refill source for pf0 (t=2,4,...)
    const ushort_t* p1 = pb + 3 * 131072;       // refill source for pf1 (t=3,5,...)

    ushort_t pf0[16], pf1[16];
#pragma unroll
    for (int ni = 0; ni < 4; ++ni)
#pragma unroll
        for (int r = 0; r < 4; ++r) {
            pf0[ni * 4 + r] = pb[r * 512 + ni * 128];
            pf1[ni * 4 + r] = p1b[r * 512 + ni * 128];
        }
    __syncthreads();

#pragma unroll 1
    for (int t = 0; t < TT; t += 2) {
        STEP(t,     pf0, p0, h0, h1);
        STEP(t + 1, pf1, p1, h1, h0);
    }

    // final dense: out[b] = h_final @ dense_w + db
    __shared__ float hf[16][256];
#pragma unroll
    for (int ni = 0; ni < 2; ++ni)
#pragma unroll
        for (int r = 0; r < 4; ++r)
            hf[q * 4 + r][(wave + 8 * ni) * 16 + lm] = cst[ni][r];
    __syncthreads();
    if (tid < 160) {
        const int bi = tid / 10, o = tid % 10;
        float acc = db[o];
#pragma unroll 8
        for (int cc = 0; cc < CC; ++cc) acc = fmaf(hf[bi][cc], dw[cc * 10 + o], acc);
        out[(g * 16 + bi) * 10 + o] = acc;
    }
}

// ---- guard ----
__global__ void ws_too_small(float* out, float wssz) {
    int i = blockIdx.x * 256 + threadIdx.x;
    if (i < BB * 10) out[i] = (i == 0) ? wssz : 0.f;
}

extern "C" void kernel_launch(void* const* d_in, const int* in_sizes, int n_in,
                              void* d_out, int out_size, void* d_ws, size_t ws_size,
                              hipStream_t stream) {
    const float* x   = (const float*)d_in[0];
    const float* kin = (const float*)d_in[1];
    const float* rk  = (const float*)d_in[2];
    const float* rb  = (const float*)d_in[3];
    const float* dw  = (const float*)d_in[4];
    const float* db  = (const float*)d_in[5];
    float* out = (float*)d_out;

    const size_t xz_bytes = (size_t)BB * TT * GG * 2;   // 268,435,456
    const size_t kt_bytes = (size_t)GG * II * 2;        // 131,072
    if (ws_size < xz_bytes + kt_bytes) {
        ws_too_small<<<10, 256, 0, stream>>>(out, (float)ws_size);
        return;
    }

    ushort_t* xz = (ushort_t*)d_ws;
    f16* kt = (f16*)((char*)d_ws + xz_bytes);

    kt_transpose<<<256, 256, 0, stream>>>(kin, kt);
    gemm_xz<<<dim3(4, 2048), 256, 0, stream>>>(x, kt, rb, xz);
    janet_rec<<<16, 512, 0, stream>>>(rk, dw, db, xz, out);
}